// Round 15
// baseline (189.522 us; speedup 1.0000x reference)
//
#include <hip/hip_runtime.h>
#include <math.h>

#define NCLS 80
#define NA 8400
#define NB 32
#define NO 144
#define PRE_TOPK 1000
#define MAX_DET 100

// ---------------- Kernel 1: cls-only decode (conf + clsid) ----------------
// Reads ONLY the 80 class channels (64..143) — the 64 DFL channels are
// gathered later for just the top-1000 anchors (k_select emit). LDS tile
// [80][64] = 20.5 KB; float4 staging; wave w handles class chunk w.
template<int HW, int WDIM>
__device__ __forceinline__ void decode_cls_blk(
    const float* __restrict__ src, int b, int a0, int aoff,
    float* __restrict__ conf, int* __restrict__ clsid, float* s_tile)
{
    int t = threadIdx.x;
    int w = t >> 6;
    int l = t & 63;

    // stage 80 channels x 64 anchors: 5 float4 loads/thread
    {
        int chl = w * 20 + (l >> 4);
        int aq = (l & 15) * 4;
        int aqc = a0 + aq; if (aqc > HW - 4) aqc = HW - 4;   // p5-tail clamp
        const float* gsrc = src + ((size_t)b * NO + 64) * HW + aqc;
        float4 stg[5];
        #pragma unroll
        for (int i = 0; i < 5; ++i)
            stg[i] = *(const float4*)(gsrc + (size_t)(chl + i * 4) * HW);
        #pragma unroll
        for (int i = 0; i < 5; ++i)
            *(float4*)&s_tile[(chl + i * 4) * 64 + aq] = stg[i];
    }
    __syncthreads();

    // wave w: class chunk w (20 logits), max + first-occurrence argmax
    float c[20];
    #pragma unroll
    for (int cc = 0; cc < 20; ++cc) c[cc] = s_tile[(w * 20 + cc) * 64 + l];
    float m = c[0]; int ii = 0;
    #pragma unroll
    for (int cc = 1; cc < 20; ++cc) if (c[cc] > m) { m = c[cc]; ii = cc; }

    __syncthreads();   // tile reads done; overlay safe

    float* s_mx = s_tile;              // [64*5]
    int*   s_id = (int*)(s_tile + 320);
    s_mx[l * 5 + w] = m;
    s_id[l * 5 + w] = w * 20 + ii;
    __syncthreads();

    if (t < 64 && a0 + t < HW) {
        float bm = s_mx[t * 5 + 0]; int bid = s_id[t * 5 + 0];
        float m1 = s_mx[t * 5 + 1]; if (m1 > bm) { bm = m1; bid = s_id[t * 5 + 1]; }
        float m2 = s_mx[t * 5 + 2]; if (m2 > bm) { bm = m2; bid = s_id[t * 5 + 2]; }
        float m3 = s_mx[t * 5 + 3]; if (m3 > bm) { bm = m3; bid = s_id[t * 5 + 3]; }
        float conf_v = 1.0f / (1.0f + __expf(-bm));   // sigmoid(max)==max(sigmoid)
        size_t gid = (size_t)b * NA + aoff + (a0 + t);
        conf[gid]  = conf_v;
        clsid[gid] = bid;
    }
}

__global__ __launch_bounds__(256) void k_decode(
    const float* __restrict__ p3, const float* __restrict__ p4, const float* __restrict__ p5,
    float* __restrict__ conf, int* __restrict__ clsid)
{
    __shared__ float s_tile[80 * 64];    // 20,480 B
    int blk = blockIdx.x;
    int b = blk / 132;
    int r = blk - b * 132;
    if (r < 100)       decode_cls_blk<6400, 80>(p3, b, r * 64, 0, conf, clsid, s_tile);
    else if (r < 125)  decode_cls_blk<1600, 40>(p4, b, (r - 100) * 64, 6400, conf, clsid, s_tile);
    else               decode_cls_blk<400, 20>(p5, b, (r - 125) * 64, 8000, conf, clsid, s_tile);
}

// ---------------- Kernel 2: top-1000 select + DFL box decode ----------------
__device__ __forceinline__ uint32_t ord_bits(float f) {
    uint32_t u = __float_as_uint(f);
    return (u & 0x80000000u) ? ~u : (u | 0x80000000u);
}

// gather 64 DFL channels for one anchor, softmax-dot, emit xyxy
__device__ __forceinline__ float4 dfl_box(const float* __restrict__ base,
                                          int HW, int pos, int WDIM, float S)
{
    float dist[4];
    #pragma unroll
    for (int s4 = 0; s4 < 4; ++s4) {
        float v[16];
        #pragma unroll
        for (int r = 0; r < 16; ++r) v[r] = base[(size_t)(s4 * 16 + r) * HW];
        float mm = v[0];
        #pragma unroll
        for (int r = 1; r < 16; ++r) mm = fmaxf(mm, v[r]);
        float sum = 0.f, d = 0.f;
        #pragma unroll
        for (int r = 0; r < 16; ++r) {
            float e = __expf(v[r] - mm);
            sum += e;
            d += e * (float)r;
        }
        dist[s4] = d * (1.0f / sum);
    }
    float ax = (float)(pos % WDIM) + 0.5f;
    float ay = (float)(pos / WDIM) + 0.5f;
    float x1 = ax - dist[0], y1 = ay - dist[1];
    float x2 = ax + dist[2], y2 = ay + dist[3];
    float cx = ((x1 + x2) * 0.5f) * S;
    float cy = ((y1 + y2) * 0.5f) * S;
    float w  = (x2 - x1) * S;
    float h  = (y2 - y1) * S;
    return make_float4(cx - w * 0.5f, cy - h * 0.5f, cx + w * 0.5f, cy + h * 0.5f);
}

__global__ __launch_bounds__(1024) void k_select(
    const float* __restrict__ conf, const int* __restrict__ clsid,
    const float* __restrict__ p3, const float* __restrict__ p4, const float* __restrict__ p5,
    float* __restrict__ topv, float* __restrict__ bxyxy, int* __restrict__ topcls)
{
    int b = blockIdx.x;
    int t = threadIdx.x;
    int lane = t & 63;

    __shared__ uint32_t hist[256];
    __shared__ uint64_t sbuf[1024];      // 8 KB
    __shared__ uint32_t s_prefix;
    __shared__ int s_k;
    __shared__ int s_cnt;

    // 9 keys/thread in registers (static indexing, full unroll)
    const float* cf = conf + (size_t)b * NA;
    uint32_t kr[9];
    #pragma unroll
    for (int p = 0; p < 9; ++p) {
        int i = t + p * 1024;
        uint32_t k = 0;
        if (i < NA) {
            float c = cf[i];
            float cm = (c > 0.25f) ? c : -1.0f;
            k = ord_bits(cm);
        }
        kr[p] = k;
    }
    if (t == 0) { s_prefix = 0; s_k = PRE_TOPK; s_cnt = 0; }
    sbuf[t] = 0;
    __syncthreads();

    // 4 radix passes over 32-bit ord(conf); wave-aggregated hist atomics
    for (int pass = 0; pass < 4; ++pass) {
        int shift = 24 - 8 * pass;
        if (t < 256) hist[t] = 0;
        __syncthreads();
        uint32_t prefix = s_prefix;
        int k = s_k;
        #pragma unroll
        for (int p = 0; p < 9; ++p) {
            int i = t + p * 1024;
            uint32_t key = kr[p];
            bool match = (i < NA) &&
                         ((pass == 0) || (((key ^ prefix) >> (32 - 8 * pass)) == 0));
            uint32_t d = (key >> shift) & 255u;
            if (match) {
                uint64_t m = __ballot(1);
                #pragma unroll
                for (int bb = 0; bb < 8; ++bb) {
                    uint64_t bal = __ballot((d >> bb) & 1u);
                    m &= ((d >> bb) & 1u) ? bal : ~bal;
                }
                if ((m & ((1ull << lane) - 1ull)) == 0ull)
                    atomicAdd(&hist[d], (uint32_t)__popcll(m));
            }
        }
        __syncthreads();
        if (t < 64) {   // wave-0 suffix-scan digit selection
            uint32_t h0 = hist[4 * t + 0], h1 = hist[4 * t + 1];
            uint32_t h2 = hist[4 * t + 2], h3 = hist[4 * t + 3];
            uint32_t part = h0 + h1 + h2 + h3;
            uint32_t s = part;
            #pragma unroll
            for (int off = 1; off < 64; off <<= 1) {
                uint32_t v = __shfl_down(s, off);
                if (t + off < 64) s += v;
            }
            uint32_t cb3 = s - part;
            uint32_t cb2 = cb3 + h3;
            uint32_t cb1 = cb2 + h2;
            uint32_t cb0 = cb1 + h1;
            uint32_t ku = (uint32_t)k;
            if (cb3 < ku && ku <= cb3 + h3) { s_k = k - (int)cb3; s_prefix = prefix | ((uint32_t)(4 * t + 3) << shift); }
            if (cb2 < ku && ku <= cb2 + h2) { s_k = k - (int)cb2; s_prefix = prefix | ((uint32_t)(4 * t + 2) << shift); }
            if (cb1 < ku && ku <= cb1 + h1) { s_k = k - (int)cb1; s_prefix = prefix | ((uint32_t)(4 * t + 1) << shift); }
            if (cb0 < ku && ku <= cb0 + h0) { s_k = k - (int)cb0; s_prefix = prefix | ((uint32_t)(4 * t + 0) << shift); }
        }
        __syncthreads();
    }

    // compact kr >= kstar (greater + equal-conf ties), build 46-bit keys
    uint32_t kstar = s_prefix;
    #pragma unroll
    for (int p = 0; p < 9; ++p) {
        int i = t + p * 1024;
        uint32_t key = kr[p];
        if (i < NA && key >= kstar) {
            int pos = atomicAdd(&s_cnt, 1);
            if (pos < 1024) sbuf[pos] = ((uint64_t)key << 14) | (uint64_t)(16383 - i);
        }
    }
    __syncthreads();

    // bitonic sort 1024 descending by (conf, -index)
    uint64_t v = sbuf[t];
    for (int k = 2; k <= 1024; k <<= 1) {
        for (int j = k >> 1; j > 0; j >>= 1) {
            uint64_t o;
            if (j >= 64) {
                sbuf[t] = v;
                __syncthreads();
                o = sbuf[t ^ j];
                __syncthreads();
            } else {
                o = __shfl_xor((unsigned long long)v, j);
            }
            bool desc  = ((t & k) == 0);
            bool lower = ((t & j) == 0);
            v = (desc == lower) ? (v > o ? v : o) : (v < o ? v : o);
        }
    }

    // emit: score/class + on-demand DFL box decode for this thread's anchor
    if (t < PRE_TOPK) {
        uint64_t key = v;
        uint32_t u = (uint32_t)(key >> 14);
        uint32_t fb = (u & 0x80000000u) ? (u ^ 0x80000000u) : ~u;
        float val = __uint_as_float(fb);
        int idx = 16383 - (int)(key & 16383u);

        float4 bb;
        if (idx < 6400) {
            const float* base = p3 + ((size_t)b * NO) * 6400 + idx;
            bb = dfl_box(base, 6400, idx, 80, 8.f);
        } else if (idx < 8000) {
            int pos = idx - 6400;
            const float* base = p4 + ((size_t)b * NO) * 1600 + pos;
            bb = dfl_box(base, 1600, pos, 40, 16.f);
        } else {
            int pos = idx - 8000;
            const float* base = p5 + ((size_t)b * NO) * 400 + pos;
            bb = dfl_box(base, 400, pos, 20, 32.f);
        }

        size_t o = (size_t)b * PRE_TOPK + t;
        topv[o] = val;
        *(float4*)(bxyxy + o * 4) = bb;
        topcls[o] = clsid[(size_t)b * NA + idx];
    }
}

// ---------------- Kernel 3: pairwise IoU bitmask (full GPU, unchanged) ------
__device__ __forceinline__ int bslot(int j) { return j + (j >> 6); }

__global__ __launch_bounds__(256) void k_iou(
    const float* __restrict__ bxyxy, unsigned long long* __restrict__ mask)
{
    __shared__ float4 boxes[PRE_TOPK + 16];   // padded: lane stride 65 float4 -> 2-way (free)
    int b = blockIdx.y;
    int t = threadIdx.x;
    const float4* bp = (const float4*)(bxyxy + (size_t)b * PRE_TOPK * 4);
    for (int i = t; i < PRE_TOPK; i += 256) boxes[bslot(i)] = bp[i];
    __syncthreads();

    int r_local = t >> 4, w = t & 15;
    int row = blockIdx.x * 16 + r_local;
    if (row >= PRE_TOPK) return;

    float4 bi = boxes[bslot(row)];
    float area_i = (bi.z - bi.x) * (bi.w - bi.y);
    unsigned long long bits = 0;
    int j0 = w * 64;
    #pragma unroll 4
    for (int jj = 0; jj < 64; ++jj) {
        int j = j0 + jj;
        if (j >= PRE_TOPK) break;
        if (j <= row) continue;
        float4 bj = boxes[bslot(j)];
        float lx = fmaxf(bi.x, bj.x), ly = fmaxf(bi.y, bj.y);
        float rx = fminf(bi.z, bj.z), ry = fminf(bi.w, bj.w);
        float iw = fmaxf(rx - lx, 0.f), ih = fmaxf(ry - ly, 0.f);
        float inter = iw * ih;
        float area_j = (bj.z - bj.x) * (bj.w - bj.y);
        float iou = inter / (area_i + area_j - inter + 1e-7f);
        if (iou > 0.45f) bits |= (1ull << jj);
    }
    mask[((size_t)b * PRE_TOPK + row) * 16 + w] = bits;
}

// ---------------- Kernel 4: leader-jump NMS walk + emit (unchanged) --------
__global__ __launch_bounds__(1024) void k_nms(
    const unsigned long long* __restrict__ mask, const float* __restrict__ topv,
    const float* __restrict__ bxyxy, const int* __restrict__ topcls,
    float* __restrict__ out)
{
    int b = blockIdx.x;
    int t = threadIdx.x;

    __shared__ __align__(16) unsigned long long smask[PRE_TOPK * 16];  // 128 KB
    __shared__ float sv[PRE_TOPK];
    __shared__ unsigned long long s_valid[16];
    __shared__ int kept[MAX_DET];
    __shared__ int s_cnt;

    for (int i = t; i < PRE_TOPK; i += 1024) sv[i] = topv[(size_t)b * PRE_TOPK + i];
    {
        const ulonglong2* src = (const ulonglong2*)(mask + (size_t)b * PRE_TOPK * 16);
        ulonglong2* dst = (ulonglong2*)smask;
        for (int i = t; i < PRE_TOPK * 8; i += 1024) dst[i] = src[i];
    }
    __syncthreads();

    {
        bool pred = (t < PRE_TOPK) && (sv[t] > 0.0f);
        unsigned long long bal = __ballot(pred);
        if ((t & 63) == 0) s_valid[t >> 6] = bal;
    }
    __syncthreads();

    if (t < 64) {   // wave 0: leader-jump walk (one iteration per KEPT box)
        int w = t;
        unsigned long long supp = 0;
        unsigned long long valid = (w < 16) ? s_valid[w] : 0ull;
        int base = w * 64;
        int cur = -1;
        int cnt = 0;
        while (cnt < MAX_DET) {
            unsigned long long gt;
            if (cur < base)            gt = ~0ull;
            else if (cur - base >= 63) gt = 0ull;
            else                       gt = (~0ull) << (cur - base + 1);
            unsigned long long cand = valid & ~supp & gt;
            int idx = cand ? (base + __builtin_ctzll(cand)) : 0x7FFFFFFF;
            #pragma unroll
            for (int off = 8; off >= 1; off >>= 1) {
                int o = __shfl_xor(idx, off);
                idx = (o < idx) ? o : idx;
            }
            int nxt = __shfl(idx, 0);
            if (nxt == 0x7FFFFFFF) break;
            if (t == 0) kept[cnt] = nxt;
            ++cnt;
            if (w < 16) supp |= smask[nxt * 16 + w];
            cur = nxt;
        }
        if (t == 0) s_cnt = cnt;
    }
    __syncthreads();

    int cnt = s_cnt; if (cnt > MAX_DET) cnt = MAX_DET;
    if (t == 0) out[b] = (float)cnt;                       // num_dets (B,1)
    if (t < MAX_DET) {
        bool valid = t < cnt;
        float bx0 = 0.f, bx1 = 0.f, bx2 = 0.f, bx3 = 0.f, sc = 0.f, cl = 0.f;
        if (valid) {
            int p = kept[t];
            size_t o = (size_t)b * PRE_TOPK + p;
            float4 bb = *(const float4*)(bxyxy + o * 4);
            bx0 = bb.x; bx1 = bb.y; bx2 = bb.z; bx3 = bb.w;
            sc = sv[p];
            cl = (float)topcls[o];
        }
        size_t db = 32 + ((size_t)b * MAX_DET + t) * 4;
        out[db + 0] = bx0; out[db + 1] = bx1; out[db + 2] = bx2; out[db + 3] = bx3;
        out[32 + 12800 + (size_t)b * MAX_DET + t] = sc;    // det_scores
        out[32 + 16000 + (size_t)b * MAX_DET + t] = cl;    // det_classes
    }
}

// ---------------- launch ----------------
extern "C" void kernel_launch(void* const* d_in, const int* in_sizes, int n_in,
                              void* d_out, int out_size, void* d_ws, size_t ws_size,
                              hipStream_t stream)
{
    const float* p3 = (const float*)d_in[0];
    const float* p4 = (const float*)d_in[1];
    const float* p5 = (const float*)d_in[2];
    float* out = (float*)d_out;

    char* ws = (char*)d_ws;
    size_t off_mask = 0;                                       // 32*1000*16*8 = 4,096,000
    size_t off_conf = off_mask + (size_t)NB * PRE_TOPK * 16 * 8;
    size_t off_cls  = off_conf + (size_t)NB * NA * 4;
    size_t off_topv = off_cls  + (size_t)NB * NA * 4;
    size_t off_topc = off_topv + (size_t)NB * PRE_TOPK * 4;
    size_t off_bx   = off_topc + (size_t)NB * PRE_TOPK * 4;

    unsigned long long* mask = (unsigned long long*)(ws + off_mask);
    float* conf   = (float*)(ws + off_conf);
    int*   clsid  = (int*)(ws + off_cls);
    float* topv   = (float*)(ws + off_topv);
    int*   topcls = (int*)(ws + off_topc);
    float* bxyxy  = (float*)(ws + off_bx);

    k_decode<<<NB * 132, 256, 0, stream>>>(p3, p4, p5, conf, clsid);
    k_select<<<NB, 1024, 0, stream>>>(conf, clsid, p3, p4, p5, topv, bxyxy, topcls);
    k_iou<<<dim3((PRE_TOPK + 15) / 16, NB), 256, 0, stream>>>(bxyxy, mask);
    k_nms<<<NB, 1024, 0, stream>>>(mask, topv, bxyxy, topcls, out);
}

// Round 16
// 131.726 us; speedup vs baseline: 1.4388x; 1.4388x over previous
//
#include <hip/hip_runtime.h>
#include <math.h>

#define NCLS 80
#define NA 8400
#define NB 32
#define NO 144
#define PRE_TOPK 1000
#define MAX_DET 100

// ---------------- Kernel 1: LDS-staged decode, 128 anchors/block ----------
// 512 threads stage a [144][128] tile (73.7 KB, 2 blocks/CU = 16 waves/CU,
// same TLP as the 64-anchor version). Each channel row is now 512 B
// contiguous (2x the previous 256 B) — tests the DRAM-segment-size theory.
// Wave instruction = 2 channels x 512 B. Compute: part p = t>>7 handles DFL
// side p + class chunk p for anchor a = t&127 (LDS reads bank-free: 128%32==0
// -> bank = a%32, distinct per lane).
template<int HW, int WDIM, int S>
__device__ __forceinline__ void decode_blk(
    const float* __restrict__ src, int b, int a0, int aoff,
    float* __restrict__ conf, int* __restrict__ clsid, float* __restrict__ box,
    float* s_tile)
{
    int t = threadIdx.x;              // 0..511

    // ---- stage 144 ch x 128 anchors: 9 float4 loads/thread ----
    {
        int chb = t >> 5;             // 0..15
        int q   = t & 31;             // anchor quad 0..31
        int aq  = q * 4;
        int aqc = a0 + aq; if (aqc > HW - 4) aqc = HW - 4;   // tail clamp
        const float* gsrc = src + ((size_t)b * NO) * HW + aqc;
        float4 stg[9];
        #pragma unroll
        for (int i = 0; i < 9; ++i)
            stg[i] = *(const float4*)(gsrc + (size_t)(chb + 16 * i) * HW);
        #pragma unroll
        for (int i = 0; i < 9; ++i)
            *(float4*)&s_tile[(chb + 16 * i) * 128 + aq] = stg[i];
    }
    __syncthreads();

    // ---- compute: part p, anchor a ----
    int p = t >> 7;                   // 0..3
    int a = t & 127;

    float v[16];
    #pragma unroll
    for (int r = 0; r < 16; ++r) v[r] = s_tile[(p * 16 + r) * 128 + a];
    float mm = v[0];
    #pragma unroll
    for (int r = 1; r < 16; ++r) mm = fmaxf(mm, v[r]);
    float sum = 0.f, d = 0.f;
    #pragma unroll
    for (int r = 0; r < 16; ++r) {
        float e = __expf(v[r] - mm);
        sum += e;
        d += e * (float)r;
    }
    d *= 1.0f / sum;

    float c[20];
    #pragma unroll
    for (int cc = 0; cc < 20; ++cc) c[cc] = s_tile[(64 + p * 20 + cc) * 128 + a];
    float m = c[0]; int ii = 0;
    #pragma unroll
    for (int cc = 1; cc < 20; ++cc) if (c[cc] > m) { m = c[cc]; ii = cc; }

    __syncthreads();   // all tile reads done; overlay safe

    float* s_dfl = s_tile;             // [128*5]
    float* s_mx  = s_tile + 640;       // [128*5]
    int*   s_id  = (int*)(s_tile + 1280);
    s_dfl[a * 5 + p] = d;
    s_mx[a * 5 + p]  = m;
    s_id[a * 5 + p]  = p * 20 + ii;
    __syncthreads();

    // waves 0-1 combine and emit 128 anchors
    if (t < 128 && a0 + t < HW) {
        int pos2 = a0 + t;
        float d0 = s_dfl[t * 5 + 0], d1 = s_dfl[t * 5 + 1];
        float d2 = s_dfl[t * 5 + 2], d3 = s_dfl[t * 5 + 3];
        float bm = s_mx[t * 5 + 0]; int bid = s_id[t * 5 + 0];
        float m1 = s_mx[t * 5 + 1]; if (m1 > bm) { bm = m1; bid = s_id[t * 5 + 1]; }
        float m2 = s_mx[t * 5 + 2]; if (m2 > bm) { bm = m2; bid = s_id[t * 5 + 2]; }
        float m3 = s_mx[t * 5 + 3]; if (m3 > bm) { bm = m3; bid = s_id[t * 5 + 3]; }
        float conf_v = 1.0f / (1.0f + __expf(-bm));   // sigmoid(max)==max(sigmoid)

        float ax = (float)(pos2 % WDIM) + 0.5f;
        float ay = (float)(pos2 / WDIM) + 0.5f;
        float x1 = ax - d0, y1 = ay - d1;
        float x2 = ax + d2, y2 = ay + d3;
        float cx = ((x1 + x2) * 0.5f) * (float)S;
        float cy = ((y1 + y2) * 0.5f) * (float)S;
        float ww = (x2 - x1) * (float)S;
        float hh = (y2 - y1) * (float)S;

        size_t gid = (size_t)b * NA + aoff + pos2;
        conf[gid]  = conf_v;
        clsid[gid] = bid;
        *(float4*)(box + gid * 4) = make_float4(cx, cy, ww, hh);
    }
}

// per batch: 50 blocks (p3) + 13 (p4) + 4 (p5) = 67
__global__ __launch_bounds__(512) void k_decode(
    const float* __restrict__ p3, const float* __restrict__ p4, const float* __restrict__ p5,
    float* __restrict__ conf, int* __restrict__ clsid, float* __restrict__ box)
{
    __shared__ float s_tile[NO * 128];   // 73,728 B
    int blk = blockIdx.x;
    int b = blk / 67;
    int r = blk - b * 67;
    if (r < 50)       decode_blk<6400, 80, 8>(p3, b, r * 128, 0, conf, clsid, box, s_tile);
    else if (r < 63)  decode_blk<1600, 40, 16>(p4, b, (r - 50) * 128, 6400, conf, clsid, box, s_tile);
    else              decode_blk<400, 20, 32>(p5, b, (r - 63) * 128, 8000, conf, clsid, box, s_tile);
}

// ---------------- Kernel 2: exact stable top-1000 per batch (R14) ----------
__device__ __forceinline__ uint32_t ord_bits(float f) {
    uint32_t u = __float_as_uint(f);
    return (u & 0x80000000u) ? ~u : (u | 0x80000000u);
}

__global__ __launch_bounds__(1024) void k_select(
    const float* __restrict__ conf, const float* __restrict__ box, const int* __restrict__ clsid,
    float* __restrict__ topv, float* __restrict__ bxyxy, int* __restrict__ topcls)
{
    int b = blockIdx.x;
    int t = threadIdx.x;
    int lane = t & 63;

    __shared__ uint32_t hist[256];
    __shared__ uint64_t sbuf[1024];      // 8 KB
    __shared__ uint32_t s_prefix;
    __shared__ int s_k;
    __shared__ int s_cnt;

    // 9 keys/thread in registers (static indexing, full unroll)
    const float* cf = conf + (size_t)b * NA;
    uint32_t kr[9];
    #pragma unroll
    for (int p = 0; p < 9; ++p) {
        int i = t + p * 1024;
        uint32_t k = 0;
        if (i < NA) {
            float c = cf[i];
            float cm = (c > 0.25f) ? c : -1.0f;
            k = ord_bits(cm);
        }
        kr[p] = k;
    }
    if (t == 0) { s_prefix = 0; s_k = PRE_TOPK; s_cnt = 0; }
    sbuf[t] = 0;
    __syncthreads();

    // 4 radix passes over 32-bit ord(conf); wave-aggregated hist atomics
    for (int pass = 0; pass < 4; ++pass) {
        int shift = 24 - 8 * pass;
        if (t < 256) hist[t] = 0;
        __syncthreads();
        uint32_t prefix = s_prefix;
        int k = s_k;
        #pragma unroll
        for (int p = 0; p < 9; ++p) {
            int i = t + p * 1024;
            uint32_t key = kr[p];
            bool match = (i < NA) &&
                         ((pass == 0) || (((key ^ prefix) >> (32 - 8 * pass)) == 0));
            uint32_t d = (key >> shift) & 255u;
            if (match) {
                uint64_t m = __ballot(1);
                #pragma unroll
                for (int bb = 0; bb < 8; ++bb) {
                    uint64_t bal = __ballot((d >> bb) & 1u);
                    m &= ((d >> bb) & 1u) ? bal : ~bal;
                }
                if ((m & ((1ull << lane) - 1ull)) == 0ull)
                    atomicAdd(&hist[d], (uint32_t)__popcll(m));
            }
        }
        __syncthreads();
        if (t < 64) {   // wave-0 suffix-scan digit selection
            uint32_t h0 = hist[4 * t + 0], h1 = hist[4 * t + 1];
            uint32_t h2 = hist[4 * t + 2], h3 = hist[4 * t + 3];
            uint32_t part = h0 + h1 + h2 + h3;
            uint32_t s = part;
            #pragma unroll
            for (int off = 1; off < 64; off <<= 1) {
                uint32_t v = __shfl_down(s, off);
                if (t + off < 64) s += v;
            }
            uint32_t cb3 = s - part;
            uint32_t cb2 = cb3 + h3;
            uint32_t cb1 = cb2 + h2;
            uint32_t cb0 = cb1 + h1;
            uint32_t ku = (uint32_t)k;
            if (cb3 < ku && ku <= cb3 + h3) { s_k = k - (int)cb3; s_prefix = prefix | ((uint32_t)(4 * t + 3) << shift); }
            if (cb2 < ku && ku <= cb2 + h2) { s_k = k - (int)cb2; s_prefix = prefix | ((uint32_t)(4 * t + 2) << shift); }
            if (cb1 < ku && ku <= cb1 + h1) { s_k = k - (int)cb1; s_prefix = prefix | ((uint32_t)(4 * t + 1) << shift); }
            if (cb0 < ku && ku <= cb0 + h0) { s_k = k - (int)cb0; s_prefix = prefix | ((uint32_t)(4 * t + 0) << shift); }
        }
        __syncthreads();
    }

    // compact kr >= kstar (greater + equal-conf ties), build 46-bit keys
    uint32_t kstar = s_prefix;
    #pragma unroll
    for (int p = 0; p < 9; ++p) {
        int i = t + p * 1024;
        uint32_t key = kr[p];
        if (i < NA && key >= kstar) {
            int pos = atomicAdd(&s_cnt, 1);
            if (pos < 1024) sbuf[pos] = ((uint64_t)key << 14) | (uint64_t)(16383 - i);
        }
    }
    __syncthreads();

    // bitonic sort 1024 descending by (conf, -index); register-resident,
    // j<64 stages via __shfl_xor (no barrier), j>=64 via LDS.
    uint64_t v = sbuf[t];
    for (int k = 2; k <= 1024; k <<= 1) {
        for (int j = k >> 1; j > 0; j >>= 1) {
            uint64_t o;
            if (j >= 64) {
                sbuf[t] = v;
                __syncthreads();
                o = sbuf[t ^ j];
                __syncthreads();
            } else {
                o = __shfl_xor((unsigned long long)v, j);
            }
            bool desc  = ((t & k) == 0);
            bool lower = ((t & j) == 0);
            v = (desc == lower) ? (v > o ? v : o) : (v < o ? v : o);
        }
    }

    if (t < PRE_TOPK) {
        uint64_t key = v;
        uint32_t u = (uint32_t)(key >> 14);
        uint32_t fb = (u & 0x80000000u) ? (u ^ 0x80000000u) : ~u;
        float val = __uint_as_float(fb);
        int idx = 16383 - (int)(key & 16383u);
        size_t g = (size_t)b * NA + idx;
        float4 bx = *(const float4*)(box + g * 4);
        float cx = bx.x, cy = bx.y, w = bx.z, h = bx.w;
        size_t o = (size_t)b * PRE_TOPK + t;
        topv[o] = val;
        *(float4*)(bxyxy + o * 4) = make_float4(cx - w * 0.5f, cy - h * 0.5f,
                                                cx + w * 0.5f, cy + h * 0.5f);
        topcls[o] = clsid[g];
    }
}

// ---------------- Kernel 3: pairwise IoU bitmask (full GPU, unchanged) ------
__device__ __forceinline__ int bslot(int j) { return j + (j >> 6); }

__global__ __launch_bounds__(256) void k_iou(
    const float* __restrict__ bxyxy, unsigned long long* __restrict__ mask)
{
    __shared__ float4 boxes[PRE_TOPK + 16];   // padded: lane stride 65 float4 -> 2-way (free)
    int b = blockIdx.y;
    int t = threadIdx.x;
    const float4* bp = (const float4*)(bxyxy + (size_t)b * PRE_TOPK * 4);
    for (int i = t; i < PRE_TOPK; i += 256) boxes[bslot(i)] = bp[i];
    __syncthreads();

    int r_local = t >> 4, w = t & 15;
    int row = blockIdx.x * 16 + r_local;
    if (row >= PRE_TOPK) return;

    float4 bi = boxes[bslot(row)];
    float area_i = (bi.z - bi.x) * (bi.w - bi.y);
    unsigned long long bits = 0;
    int j0 = w * 64;
    #pragma unroll 4
    for (int jj = 0; jj < 64; ++jj) {
        int j = j0 + jj;
        if (j >= PRE_TOPK) break;
        if (j <= row) continue;
        float4 bj = boxes[bslot(j)];
        float lx = fmaxf(bi.x, bj.x), ly = fmaxf(bi.y, bj.y);
        float rx = fminf(bi.z, bj.z), ry = fminf(bi.w, bj.w);
        float iw = fmaxf(rx - lx, 0.f), ih = fmaxf(ry - ly, 0.f);
        float inter = iw * ih;
        float area_j = (bj.z - bj.x) * (bj.w - bj.y);
        float iou = inter / (area_i + area_j - inter + 1e-7f);
        if (iou > 0.45f) bits |= (1ull << jj);
    }
    mask[((size_t)b * PRE_TOPK + row) * 16 + w] = bits;
}

// ---------------- Kernel 4: leader-jump NMS walk + emit (unchanged) --------
__global__ __launch_bounds__(1024) void k_nms(
    const unsigned long long* __restrict__ mask, const float* __restrict__ topv,
    const float* __restrict__ bxyxy, const int* __restrict__ topcls,
    float* __restrict__ out)
{
    int b = blockIdx.x;
    int t = threadIdx.x;

    __shared__ __align__(16) unsigned long long smask[PRE_TOPK * 16];  // 128 KB
    __shared__ float sv[PRE_TOPK];
    __shared__ unsigned long long s_valid[16];
    __shared__ int kept[MAX_DET];
    __shared__ int s_cnt;

    for (int i = t; i < PRE_TOPK; i += 1024) sv[i] = topv[(size_t)b * PRE_TOPK + i];
    {
        const ulonglong2* src = (const ulonglong2*)(mask + (size_t)b * PRE_TOPK * 16);
        ulonglong2* dst = (ulonglong2*)smask;
        for (int i = t; i < PRE_TOPK * 8; i += 1024) dst[i] = src[i];
    }
    __syncthreads();

    {
        bool pred = (t < PRE_TOPK) && (sv[t] > 0.0f);
        unsigned long long bal = __ballot(pred);
        if ((t & 63) == 0) s_valid[t >> 6] = bal;
    }
    __syncthreads();

    if (t < 64) {   // wave 0: leader-jump walk (one iteration per KEPT box)
        int w = t;
        unsigned long long supp = 0;
        unsigned long long valid = (w < 16) ? s_valid[w] : 0ull;
        int base = w * 64;
        int cur = -1;
        int cnt = 0;
        while (cnt < MAX_DET) {
            unsigned long long gt;
            if (cur < base)            gt = ~0ull;
            else if (cur - base >= 63) gt = 0ull;
            else                       gt = (~0ull) << (cur - base + 1);
            unsigned long long cand = valid & ~supp & gt;
            int idx = cand ? (base + __builtin_ctzll(cand)) : 0x7FFFFFFF;
            #pragma unroll
            for (int off = 8; off >= 1; off >>= 1) {
                int o = __shfl_xor(idx, off);
                idx = (o < idx) ? o : idx;
            }
            int nxt = __shfl(idx, 0);
            if (nxt == 0x7FFFFFFF) break;
            if (t == 0) kept[cnt] = nxt;
            ++cnt;
            if (w < 16) supp |= smask[nxt * 16 + w];
            cur = nxt;
        }
        if (t == 0) s_cnt = cnt;
    }
    __syncthreads();

    int cnt = s_cnt; if (cnt > MAX_DET) cnt = MAX_DET;
    if (t == 0) out[b] = (float)cnt;                       // num_dets (B,1)
    if (t < MAX_DET) {
        bool valid = t < cnt;
        float bx0 = 0.f, bx1 = 0.f, bx2 = 0.f, bx3 = 0.f, sc = 0.f, cl = 0.f;
        if (valid) {
            int p = kept[t];
            size_t o = (size_t)b * PRE_TOPK + p;
            float4 bb = *(const float4*)(bxyxy + o * 4);
            bx0 = bb.x; bx1 = bb.y; bx2 = bb.z; bx3 = bb.w;
            sc = sv[p];
            cl = (float)topcls[o];
        }
        size_t db = 32 + ((size_t)b * MAX_DET + t) * 4;
        out[db + 0] = bx0; out[db + 1] = bx1; out[db + 2] = bx2; out[db + 3] = bx3;
        out[32 + 12800 + (size_t)b * MAX_DET + t] = sc;    // det_scores
        out[32 + 16000 + (size_t)b * MAX_DET + t] = cl;    // det_classes
    }
}

// ---------------- launch ----------------
extern "C" void kernel_launch(void* const* d_in, const int* in_sizes, int n_in,
                              void* d_out, int out_size, void* d_ws, size_t ws_size,
                              hipStream_t stream)
{
    const float* p3 = (const float*)d_in[0];
    const float* p4 = (const float*)d_in[1];
    const float* p5 = (const float*)d_in[2];
    float* out = (float*)d_out;

    char* ws = (char*)d_ws;
    size_t off_mask = 0;                                       // 32*1000*16*8 = 4,096,000
    size_t off_conf = off_mask + (size_t)NB * PRE_TOPK * 16 * 8;
    size_t off_cls  = off_conf + (size_t)NB * NA * 4;
    size_t off_box  = off_cls  + (size_t)NB * NA * 4;
    size_t off_topv = off_box  + (size_t)NB * NA * 4 * 4;
    size_t off_topc = off_topv + (size_t)NB * PRE_TOPK * 4;
    size_t off_bx   = off_topc + (size_t)NB * PRE_TOPK * 4;

    unsigned long long* mask = (unsigned long long*)(ws + off_mask);
    float* conf   = (float*)(ws + off_conf);
    int*   clsid  = (int*)(ws + off_cls);
    float* box    = (float*)(ws + off_box);
    float* topv   = (float*)(ws + off_topv);
    int*   topcls = (int*)(ws + off_topc);
    float* bxyxy  = (float*)(ws + off_bx);

    k_decode<<<NB * 67, 512, 0, stream>>>(p3, p4, p5, conf, clsid, box);
    k_select<<<NB, 1024, 0, stream>>>(conf, box, clsid, topv, bxyxy, topcls);
    k_iou<<<dim3((PRE_TOPK + 15) / 16, NB), 256, 0, stream>>>(bxyxy, mask);
    k_nms<<<NB, 1024, 0, stream>>>(mask, topv, bxyxy, topcls, out);
}

// Round 17
// 131.342 us; speedup vs baseline: 1.4430x; 1.0029x over previous
//
#include <hip/hip_runtime.h>
#include <math.h>

#define NCLS 80
#define NA 8400
#define NB 32
#define NO 144
#define PRE_TOPK 1000
#define MAX_DET 100

typedef const __attribute__((address_space(1))) void g_void;
typedef __attribute__((address_space(3))) void l_void;

// ---------------- Kernel 1: decode with async global->LDS staging ----------
// Same [144][128] tile / 512-thread structure as R16, but staging uses
// __builtin_amdgcn_global_load_lds width=16: no VGPR round-trip, no ds_write
// chain — each wave issues 9 fire-and-forget loads; one vmcnt drain at the
// barrier. Per wave-instr: LDS dest = uniform base + lane*16B (lanes 0-31 =
// channel c segment, lanes 32-63 = channel c+1) — matches m104 semantics.
template<int HW, int WDIM, int S>
__device__ __forceinline__ void decode_blk(
    const float* __restrict__ src, int b, int a0, int aoff,
    float* __restrict__ conf, int* __restrict__ clsid, float* __restrict__ box,
    float* s_tile)
{
    int t = threadIdx.x;              // 0..511

    // ---- stage 144 ch x 128 anchors: 9 async 16B loads/lane ----
    {
        int wv   = t >> 6;                         // wave 0..7
        int lane = t & 63;
        int chl  = wv * 2 + (lane >> 5);           // per-lane channel
        int aq   = (lane & 31) * 4;
        int aqc  = a0 + aq; if (aqc > HW - 4) aqc = HW - 4;   // tail clamp
        const float* gsrc = src + ((size_t)b * NO) * HW + aqc;
        #pragma unroll
        for (int i = 0; i < 9; ++i) {
            const float* gp = gsrc + (size_t)(chl + 16 * i) * HW;
            float* lp = &s_tile[(wv * 2 + 16 * i) * 128];     // wave-uniform base
            __builtin_amdgcn_global_load_lds((g_void*)gp, (l_void*)lp, 16, 0, 0);
        }
    }
    __syncthreads();

    // ---- compute: part p, anchor a (bank-free: stride 128) ----
    int p = t >> 7;                   // 0..3
    int a = t & 127;

    float v[16];
    #pragma unroll
    for (int r = 0; r < 16; ++r) v[r] = s_tile[(p * 16 + r) * 128 + a];
    float mm = v[0];
    #pragma unroll
    for (int r = 1; r < 16; ++r) mm = fmaxf(mm, v[r]);
    float sum = 0.f, d = 0.f;
    #pragma unroll
    for (int r = 0; r < 16; ++r) {
        float e = __expf(v[r] - mm);
        sum += e;
        d += e * (float)r;
    }
    d *= 1.0f / sum;

    float c[20];
    #pragma unroll
    for (int cc = 0; cc < 20; ++cc) c[cc] = s_tile[(64 + p * 20 + cc) * 128 + a];
    float m = c[0]; int ii = 0;
    #pragma unroll
    for (int cc = 1; cc < 20; ++cc) if (c[cc] > m) { m = c[cc]; ii = cc; }

    __syncthreads();   // all tile reads done; overlay safe

    float* s_dfl = s_tile;             // [128*5]
    float* s_mx  = s_tile + 640;       // [128*5]
    int*   s_id  = (int*)(s_tile + 1280);
    s_dfl[a * 5 + p] = d;
    s_mx[a * 5 + p]  = m;
    s_id[a * 5 + p]  = p * 20 + ii;
    __syncthreads();

    // waves 0-1 combine and emit 128 anchors
    if (t < 128 && a0 + t < HW) {
        int pos2 = a0 + t;
        float d0 = s_dfl[t * 5 + 0], d1 = s_dfl[t * 5 + 1];
        float d2 = s_dfl[t * 5 + 2], d3 = s_dfl[t * 5 + 3];
        float bm = s_mx[t * 5 + 0]; int bid = s_id[t * 5 + 0];
        float m1 = s_mx[t * 5 + 1]; if (m1 > bm) { bm = m1; bid = s_id[t * 5 + 1]; }
        float m2 = s_mx[t * 5 + 2]; if (m2 > bm) { bm = m2; bid = s_id[t * 5 + 2]; }
        float m3 = s_mx[t * 5 + 3]; if (m3 > bm) { bm = m3; bid = s_id[t * 5 + 3]; }
        float conf_v = 1.0f / (1.0f + __expf(-bm));   // sigmoid(max)==max(sigmoid)

        float ax = (float)(pos2 % WDIM) + 0.5f;
        float ay = (float)(pos2 / WDIM) + 0.5f;
        float x1 = ax - d0, y1 = ay - d1;
        float x2 = ax + d2, y2 = ay + d3;
        float cx = ((x1 + x2) * 0.5f) * (float)S;
        float cy = ((y1 + y2) * 0.5f) * (float)S;
        float ww = (x2 - x1) * (float)S;
        float hh = (y2 - y1) * (float)S;

        size_t gid = (size_t)b * NA + aoff + pos2;
        conf[gid]  = conf_v;
        clsid[gid] = bid;
        *(float4*)(box + gid * 4) = make_float4(cx, cy, ww, hh);
    }
}

// per batch: 50 blocks (p3) + 13 (p4) + 4 (p5) = 67
__global__ __launch_bounds__(512) void k_decode(
    const float* __restrict__ p3, const float* __restrict__ p4, const float* __restrict__ p5,
    float* __restrict__ conf, int* __restrict__ clsid, float* __restrict__ box)
{
    __shared__ float s_tile[NO * 128];   // 73,728 B
    int blk = blockIdx.x;
    int b = blk / 67;
    int r = blk - b * 67;
    if (r < 50)       decode_blk<6400, 80, 8>(p3, b, r * 128, 0, conf, clsid, box, s_tile);
    else if (r < 63)  decode_blk<1600, 40, 16>(p4, b, (r - 50) * 128, 6400, conf, clsid, box, s_tile);
    else              decode_blk<400, 20, 32>(p5, b, (r - 63) * 128, 8000, conf, clsid, box, s_tile);
}

// ---------------- Kernel 2: exact stable top-1000 per batch (R14) ----------
__device__ __forceinline__ uint32_t ord_bits(float f) {
    uint32_t u = __float_as_uint(f);
    return (u & 0x80000000u) ? ~u : (u | 0x80000000u);
}

__global__ __launch_bounds__(1024) void k_select(
    const float* __restrict__ conf, const float* __restrict__ box, const int* __restrict__ clsid,
    float* __restrict__ topv, float* __restrict__ bxyxy, int* __restrict__ topcls)
{
    int b = blockIdx.x;
    int t = threadIdx.x;
    int lane = t & 63;

    __shared__ uint32_t hist[256];
    __shared__ uint64_t sbuf[1024];      // 8 KB
    __shared__ uint32_t s_prefix;
    __shared__ int s_k;
    __shared__ int s_cnt;

    // 9 keys/thread in registers (static indexing, full unroll)
    const float* cf = conf + (size_t)b * NA;
    uint32_t kr[9];
    #pragma unroll
    for (int p = 0; p < 9; ++p) {
        int i = t + p * 1024;
        uint32_t k = 0;
        if (i < NA) {
            float c = cf[i];
            float cm = (c > 0.25f) ? c : -1.0f;
            k = ord_bits(cm);
        }
        kr[p] = k;
    }
    if (t == 0) { s_prefix = 0; s_k = PRE_TOPK; s_cnt = 0; }
    sbuf[t] = 0;
    __syncthreads();

    // 4 radix passes over 32-bit ord(conf); wave-aggregated hist atomics
    for (int pass = 0; pass < 4; ++pass) {
        int shift = 24 - 8 * pass;
        if (t < 256) hist[t] = 0;
        __syncthreads();
        uint32_t prefix = s_prefix;
        int k = s_k;
        #pragma unroll
        for (int p = 0; p < 9; ++p) {
            int i = t + p * 1024;
            uint32_t key = kr[p];
            bool match = (i < NA) &&
                         ((pass == 0) || (((key ^ prefix) >> (32 - 8 * pass)) == 0));
            uint32_t d = (key >> shift) & 255u;
            if (match) {
                uint64_t m = __ballot(1);
                #pragma unroll
                for (int bb = 0; bb < 8; ++bb) {
                    uint64_t bal = __ballot((d >> bb) & 1u);
                    m &= ((d >> bb) & 1u) ? bal : ~bal;
                }
                if ((m & ((1ull << lane) - 1ull)) == 0ull)
                    atomicAdd(&hist[d], (uint32_t)__popcll(m));
            }
        }
        __syncthreads();
        if (t < 64) {   // wave-0 suffix-scan digit selection
            uint32_t h0 = hist[4 * t + 0], h1 = hist[4 * t + 1];
            uint32_t h2 = hist[4 * t + 2], h3 = hist[4 * t + 3];
            uint32_t part = h0 + h1 + h2 + h3;
            uint32_t s = part;
            #pragma unroll
            for (int off = 1; off < 64; off <<= 1) {
                uint32_t v = __shfl_down(s, off);
                if (t + off < 64) s += v;
            }
            uint32_t cb3 = s - part;
            uint32_t cb2 = cb3 + h3;
            uint32_t cb1 = cb2 + h2;
            uint32_t cb0 = cb1 + h1;
            uint32_t ku = (uint32_t)k;
            if (cb3 < ku && ku <= cb3 + h3) { s_k = k - (int)cb3; s_prefix = prefix | ((uint32_t)(4 * t + 3) << shift); }
            if (cb2 < ku && ku <= cb2 + h2) { s_k = k - (int)cb2; s_prefix = prefix | ((uint32_t)(4 * t + 2) << shift); }
            if (cb1 < ku && ku <= cb1 + h1) { s_k = k - (int)cb1; s_prefix = prefix | ((uint32_t)(4 * t + 1) << shift); }
            if (cb0 < ku && ku <= cb0 + h0) { s_k = k - (int)cb0; s_prefix = prefix | ((uint32_t)(4 * t + 0) << shift); }
        }
        __syncthreads();
    }

    // compact kr >= kstar (greater + equal-conf ties), build 46-bit keys
    uint32_t kstar = s_prefix;
    #pragma unroll
    for (int p = 0; p < 9; ++p) {
        int i = t + p * 1024;
        uint32_t key = kr[p];
        if (i < NA && key >= kstar) {
            int pos = atomicAdd(&s_cnt, 1);
            if (pos < 1024) sbuf[pos] = ((uint64_t)key << 14) | (uint64_t)(16383 - i);
        }
    }
    __syncthreads();

    // bitonic sort 1024 descending by (conf, -index); register-resident,
    // j<64 stages via __shfl_xor (no barrier), j>=64 via LDS.
    uint64_t v = sbuf[t];
    for (int k = 2; k <= 1024; k <<= 1) {
        for (int j = k >> 1; j > 0; j >>= 1) {
            uint64_t o;
            if (j >= 64) {
                sbuf[t] = v;
                __syncthreads();
                o = sbuf[t ^ j];
                __syncthreads();
            } else {
                o = __shfl_xor((unsigned long long)v, j);
            }
            bool desc  = ((t & k) == 0);
            bool lower = ((t & j) == 0);
            v = (desc == lower) ? (v > o ? v : o) : (v < o ? v : o);
        }
    }

    if (t < PRE_TOPK) {
        uint64_t key = v;
        uint32_t u = (uint32_t)(key >> 14);
        uint32_t fb = (u & 0x80000000u) ? (u ^ 0x80000000u) : ~u;
        float val = __uint_as_float(fb);
        int idx = 16383 - (int)(key & 16383u);
        size_t g = (size_t)b * NA + idx;
        float4 bx = *(const float4*)(box + g * 4);
        float cx = bx.x, cy = bx.y, w = bx.z, h = bx.w;
        size_t o = (size_t)b * PRE_TOPK + t;
        topv[o] = val;
        *(float4*)(bxyxy + o * 4) = make_float4(cx - w * 0.5f, cy - h * 0.5f,
                                                cx + w * 0.5f, cy + h * 0.5f);
        topcls[o] = clsid[g];
    }
}

// ---------------- Kernel 3: pairwise IoU bitmask (full GPU, unchanged) ------
__device__ __forceinline__ int bslot(int j) { return j + (j >> 6); }

__global__ __launch_bounds__(256) void k_iou(
    const float* __restrict__ bxyxy, unsigned long long* __restrict__ mask)
{
    __shared__ float4 boxes[PRE_TOPK + 16];   // padded: lane stride 65 float4 -> 2-way (free)
    int b = blockIdx.y;
    int t = threadIdx.x;
    const float4* bp = (const float4*)(bxyxy + (size_t)b * PRE_TOPK * 4);
    for (int i = t; i < PRE_TOPK; i += 256) boxes[bslot(i)] = bp[i];
    __syncthreads();

    int r_local = t >> 4, w = t & 15;
    int row = blockIdx.x * 16 + r_local;
    if (row >= PRE_TOPK) return;

    float4 bi = boxes[bslot(row)];
    float area_i = (bi.z - bi.x) * (bi.w - bi.y);
    unsigned long long bits = 0;
    int j0 = w * 64;
    #pragma unroll 4
    for (int jj = 0; jj < 64; ++jj) {
        int j = j0 + jj;
        if (j >= PRE_TOPK) break;
        if (j <= row) continue;
        float4 bj = boxes[bslot(j)];
        float lx = fmaxf(bi.x, bj.x), ly = fmaxf(bi.y, bj.y);
        float rx = fminf(bi.z, bj.z), ry = fminf(bi.w, bj.w);
        float iw = fmaxf(rx - lx, 0.f), ih = fmaxf(ry - ly, 0.f);
        float inter = iw * ih;
        float area_j = (bj.z - bj.x) * (bj.w - bj.y);
        float iou = inter / (area_i + area_j - inter + 1e-7f);
        if (iou > 0.45f) bits |= (1ull << jj);
    }
    mask[((size_t)b * PRE_TOPK + row) * 16 + w] = bits;
}

// ---------------- Kernel 4: leader-jump NMS walk + emit (unchanged) --------
__global__ __launch_bounds__(1024) void k_nms(
    const unsigned long long* __restrict__ mask, const float* __restrict__ topv,
    const float* __restrict__ bxyxy, const int* __restrict__ topcls,
    float* __restrict__ out)
{
    int b = blockIdx.x;
    int t = threadIdx.x;

    __shared__ __align__(16) unsigned long long smask[PRE_TOPK * 16];  // 128 KB
    __shared__ float sv[PRE_TOPK];
    __shared__ unsigned long long s_valid[16];
    __shared__ int kept[MAX_DET];
    __shared__ int s_cnt;

    for (int i = t; i < PRE_TOPK; i += 1024) sv[i] = topv[(size_t)b * PRE_TOPK + i];
    {
        const ulonglong2* src = (const ulonglong2*)(mask + (size_t)b * PRE_TOPK * 16);
        ulonglong2* dst = (ulonglong2*)smask;
        for (int i = t; i < PRE_TOPK * 8; i += 1024) dst[i] = src[i];
    }
    __syncthreads();

    {
        bool pred = (t < PRE_TOPK) && (sv[t] > 0.0f);
        unsigned long long bal = __ballot(pred);
        if ((t & 63) == 0) s_valid[t >> 6] = bal;
    }
    __syncthreads();

    if (t < 64) {   // wave 0: leader-jump walk (one iteration per KEPT box)
        int w = t;
        unsigned long long supp = 0;
        unsigned long long valid = (w < 16) ? s_valid[w] : 0ull;
        int base = w * 64;
        int cur = -1;
        int cnt = 0;
        while (cnt < MAX_DET) {
            unsigned long long gt;
            if (cur < base)            gt = ~0ull;
            else if (cur - base >= 63) gt = 0ull;
            else                       gt = (~0ull) << (cur - base + 1);
            unsigned long long cand = valid & ~supp & gt;
            int idx = cand ? (base + __builtin_ctzll(cand)) : 0x7FFFFFFF;
            #pragma unroll
            for (int off = 8; off >= 1; off >>= 1) {
                int o = __shfl_xor(idx, off);
                idx = (o < idx) ? o : idx;
            }
            int nxt = __shfl(idx, 0);
            if (nxt == 0x7FFFFFFF) break;
            if (t == 0) kept[cnt] = nxt;
            ++cnt;
            if (w < 16) supp |= smask[nxt * 16 + w];
            cur = nxt;
        }
        if (t == 0) s_cnt = cnt;
    }
    __syncthreads();

    int cnt = s_cnt; if (cnt > MAX_DET) cnt = MAX_DET;
    if (t == 0) out[b] = (float)cnt;                       // num_dets (B,1)
    if (t < MAX_DET) {
        bool valid = t < cnt;
        float bx0 = 0.f, bx1 = 0.f, bx2 = 0.f, bx3 = 0.f, sc = 0.f, cl = 0.f;
        if (valid) {
            int p = kept[t];
            size_t o = (size_t)b * PRE_TOPK + p;
            float4 bb = *(const float4*)(bxyxy + o * 4);
            bx0 = bb.x; bx1 = bb.y; bx2 = bb.z; bx3 = bb.w;
            sc = sv[p];
            cl = (float)topcls[o];
        }
        size_t db = 32 + ((size_t)b * MAX_DET + t) * 4;
        out[db + 0] = bx0; out[db + 1] = bx1; out[db + 2] = bx2; out[db + 3] = bx3;
        out[32 + 12800 + (size_t)b * MAX_DET + t] = sc;    // det_scores
        out[32 + 16000 + (size_t)b * MAX_DET + t] = cl;    // det_classes
    }
}

// ---------------- launch ----------------
extern "C" void kernel_launch(void* const* d_in, const int* in_sizes, int n_in,
                              void* d_out, int out_size, void* d_ws, size_t ws_size,
                              hipStream_t stream)
{
    const float* p3 = (const float*)d_in[0];
    const float* p4 = (const float*)d_in[1];
    const float* p5 = (const float*)d_in[2];
    float* out = (float*)d_out;

    char* ws = (char*)d_ws;
    size_t off_mask = 0;                                       // 32*1000*16*8 = 4,096,000
    size_t off_conf = off_mask + (size_t)NB * PRE_TOPK * 16 * 8;
    size_t off_cls  = off_conf + (size_t)NB * NA * 4;
    size_t off_box  = off_cls  + (size_t)NB * NA * 4;
    size_t off_topv = off_box  + (size_t)NB * NA * 4 * 4;
    size_t off_topc = off_topv + (size_t)NB * PRE_TOPK * 4;
    size_t off_bx   = off_topc + (size_t)NB * PRE_TOPK * 4;

    unsigned long long* mask = (unsigned long long*)(ws + off_mask);
    float* conf   = (float*)(ws + off_conf);
    int*   clsid  = (int*)(ws + off_cls);
    float* box    = (float*)(ws + off_box);
    float* topv   = (float*)(ws + off_topv);
    int*   topcls = (int*)(ws + off_topc);
    float* bxyxy  = (float*)(ws + off_bx);

    k_decode<<<NB * 67, 512, 0, stream>>>(p3, p4, p5, conf, clsid, box);
    k_select<<<NB, 1024, 0, stream>>>(conf, box, clsid, topv, bxyxy, topcls);
    k_iou<<<dim3((PRE_TOPK + 15) / 16, NB), 256, 0, stream>>>(bxyxy, mask);
    k_nms<<<NB, 1024, 0, stream>>>(mask, topv, bxyxy, topcls, out);
}